// Round 1
// 5560.999 us; speedup vs baseline: 1.0056x; 1.0056x over previous
//
#include <hip/hip_runtime.h>
#include <cstdint>

// ---------------- problem constants ----------------
#define TT 512
#define BB 64
#define DD 1024
#define HH 1024
#define NWG 128          // persistent workgroups; each owns 8 hidden units (32 gate cols)

typedef __attribute__((ext_vector_type(8))) __bf16 bf16x8;
typedef __attribute__((ext_vector_type(4))) float f32x4;

// ---- workspace layout (bytes) ----
#define WS_XQ    0
#define WS_WHB   67108864ULL
#define WS_HQ    83886080ULL
#define WS_FLAGS 151126016ULL
#define FLAGS_BYTES ((TT + 1) * NWG * 4)

__device__ __forceinline__ unsigned short f2bf(float f) {
    unsigned int u = __float_as_uint(f);
    u = (u + 0x7fffu + ((u >> 16) & 1u)) >> 16;
    return (unsigned short)u;
}

__device__ __forceinline__ float sigm(float x) {
    return 1.0f / (1.0f + __expf(-x));
}
__device__ __forceinline__ float tanh_f(float x) {
    float a = fabsf(x);
    float e = __expf(-2.0f * a);
    float t = (1.0f - e) / (1.0f + e);
    return copysignf(t, x);
}

__device__ __forceinline__ unsigned long long pack4bf(float a, float b, float c, float d) {
    return (unsigned long long)f2bf(a)
         | ((unsigned long long)f2bf(b) << 16)
         | ((unsigned long long)f2bf(c) << 32)
         | ((unsigned long long)f2bf(d) << 48);
}

// ---------------- kernel 1: convert X fp32 -> bf16 ----------------
__global__ void cvt_x(const float* __restrict__ X, unsigned short* __restrict__ Xq) {
    int i = blockIdx.x * blockDim.x + threadIdx.x;   // one thread per 8 elems
    const int n8 = TT * BB * DD / 8;
    if (i >= n8) return;
    const float4* s = (const float4*)X;
    float4 a = s[2 * i], b = s[2 * i + 1];
    union { unsigned short u[8]; uint4 q; } r;
    r.u[0] = f2bf(a.x); r.u[1] = f2bf(a.y); r.u[2] = f2bf(a.z); r.u[3] = f2bf(a.w);
    r.u[4] = f2bf(b.x); r.u[5] = f2bf(b.y); r.u[6] = f2bf(b.z); r.u[7] = f2bf(b.w);
    ((uint4*)Xq)[i] = r.q;
}

// ---------------- kernel 2: pack [Wx;Wh] into per-wave B-register order ----------------
// Linear element order: ((((wg*4 + kq)*16 + s)*2 + ct)*64 + lane)*8 + m
// lane holds B[k_global = kq*512 + s*32 + (lane>>4)*8 + m][col = ct*16 + (lane&15)]
// col j (0..31): gate = j>>3 (i,f,o,c), h = wg*8 + (j&7). k<1024 -> Wx row k, else Wh row k-1024.
__global__ void pack_w(const float* __restrict__ Wxi, const float* __restrict__ Wxf,
                       const float* __restrict__ Wxo, const float* __restrict__ Wxc,
                       const float* __restrict__ Whi, const float* __restrict__ Whf,
                       const float* __restrict__ Who, const float* __restrict__ Whc,
                       unsigned short* __restrict__ WhB) {
    int tid = blockIdx.x * blockDim.x + threadIdx.x;      // 0 .. 1,048,575 (one per 8 elems)
    int lane = tid & 63;
    int ct   = (tid >> 6) & 1;
    int s    = (tid >> 7) & 15;
    int kq   = (tid >> 11) & 3;
    int wg   = tid >> 13;
    int col  = ct * 16 + (lane & 15);
    int gate = col >> 3;
    int h    = wg * 8 + (col & 7);
    int kb   = kq * 512 + s * 32 + ((lane >> 4) & 3) * 8;   // k of element m=0

    const float* Wx[4] = {Wxi, Wxf, Wxo, Wxc};
    const float* Wh[4] = {Whi, Whf, Who, Whc};
    const float* W = (kb < 1024) ? (Wx[gate] + (size_t)kb * HH + h)
                                 : (Wh[gate] + (size_t)(kb - 1024) * HH + h);
    union { unsigned short u[8]; uint4 q; } r;
#pragma unroll
    for (int m = 0; m < 8; ++m) r.u[m] = f2bf(W[(size_t)m * HH]);
    *(uint4*)(WhB + (size_t)tid * 8) = r.q;
}

// ---------------- kernel 3: persistent LSTM recurrence ----------------
// 128 WGs x 512 threads (8 waves). Waves 0-3: X part (kq 0,1 x rhalf).
// Waves 4-7: H part (kq 2,3 x rhalf) — poll flags, then read Hq[t].
// Waves 4,5 additionally run the activation phase (128 threads, one
// (row, 4-consecutive-h) group each) and store Hq/out DIRECTLY from
// registers: no htile, one fewer barrier, fp32 out stores issued AFTER
// the flag so their HBM ack is off the critical path.
//
// SYNC DESIGN (unchanged semantics): relaxed AGENT-scope atomic stores for
// Hq data (sc1 -> LLC, fresh address each step); targeted per-wave
// s_waitcnt vmcnt(0) (inline asm) drains the Hq stores; LDS handshake
// between the two act waves; then relaxed AGENT flag store.
__global__ void __launch_bounds__(512, 2)
lstm_seq(const unsigned short* __restrict__ Xq, const unsigned short* __restrict__ WhB,
         unsigned short* __restrict__ Hq, int* flags,
         const float* __restrict__ H0, const float* __restrict__ C0,
         const float* __restrict__ bi, const float* __restrict__ bfp,
         const float* __restrict__ bo, const float* __restrict__ bc,
         float* __restrict__ out) {
    __shared__ float gpart[4][64][37];   // pad 37: act reads (r2*37) -> stride-5 banks, conflict-free
    __shared__ int hs;                   // act-wave handshake counter

    const int wg    = blockIdx.x;
    const int tid   = threadIdx.x;
    const int wv    = tid >> 6;
    const int lane  = tid & 63;
    const int quad  = lane >> 4;
    const int l15   = lane & 15;
    const int rhalf = wv & 1;
    const bool isH  = (wv >= 4);
    const int kq    = isH ? 2 + ((wv - 4) >> 1) : (wv >> 1);   // global K-quarter 0..3
    const int arow0 = rhalf * 32 + l15;      // GEMM A row for rt=0 (rt=1 adds 16)

    // activation identity: waves 4,5 -> one (row r2, 4-col group) per thread
    const bool isAct = (wv == 4) || (wv == 5);
    const int aidx   = tid - 256;            // 0..127 for act threads
    const int r2     = aidx >> 1;            // batch row 0..63
    const int ahalf  = aidx & 1;             // which 4-col half of the 8 h-cols
    const int hcol0  = wg * 8 + ahalf * 4;

    float Bi[4], Bf[4], Bo[4], Bc[4], Cr[4];
    if (isAct) {
#pragma unroll
        for (int j = 0; j < 4; ++j) {
            Bi[j] = bi[hcol0 + j];
            Bf[j] = bfp[hcol0 + j];
            Bo[j] = bo[hcol0 + j];
            Bc[j] = bc[hcol0 + j];
            Cr[j] = C0[(size_t)r2 * HH + hcol0 + j];
        }
    }

    // ---- preload this wave's 32 B-fragments (live in AGPR/VGPR unified file) ----
    bf16x8 Breg[16][2];
    {
        const unsigned short* wp = WhB + (size_t)(wg * 4 + kq) * (16 * 2 * 64 * 8);
#pragma unroll
        for (int s = 0; s < 16; ++s)
#pragma unroll
            for (int ct = 0; ct < 2; ++ct)
                Breg[s][ct] = *(const bf16x8*)(wp + ((s * 2 + ct) * 64 + lane) * 8);
    }

    // ---- publish Hq[0] slice (relaxed agent -> LLC), barrier, then relaxed flag ----
    if (tid == 0) hs = 0;
    if (tid < 64) {
        const float* s = H0 + (size_t)tid * HH + wg * 8;
        unsigned long long a = pack4bf(s[0], s[1], s[2], s[3]);
        unsigned long long b = pack4bf(s[4], s[5], s[6], s[7]);
        unsigned long long* d = (unsigned long long*)(Hq + (size_t)tid * HH + wg * 8);
        __hip_atomic_store(d,     a, __ATOMIC_RELAXED, __HIP_MEMORY_SCOPE_AGENT);
        __hip_atomic_store(d + 1, b, __ATOMIC_RELAXED, __HIP_MEMORY_SCOPE_AGENT);
    }
    __syncthreads();   // drains vmcnt -> Hq[0] visible at LLC
    if (tid == 0)
        __hip_atomic_store(&flags[wg], 1, __ATOMIC_RELAXED, __HIP_MEMORY_SCOPE_AGENT);

    for (int t = 0; t < TT; ++t) {
        f32x4 a00 = {0.f,0.f,0.f,0.f}, a01 = {0.f,0.f,0.f,0.f};
        f32x4 a10 = {0.f,0.f,0.f,0.f}, a11 = {0.f,0.f,0.f,0.f};

        if (!isH) {
            // ---- X part: no cross-WG dependency, overlaps the H waves' poll ----
            const unsigned short* xb = Xq + ((size_t)(t * BB + arow0)) * DD + kq * 512 + quad * 8;
#pragma unroll
            for (int s = 0; s < 16; ++s) {
                bf16x8 af0 = *(const bf16x8*)(xb + s * 32);
                bf16x8 af1 = *(const bf16x8*)(xb + 16 * DD + s * 32);
                a00 = __builtin_amdgcn_mfma_f32_16x16x32_bf16(af0, Breg[s][0], a00, 0, 0, 0);
                a01 = __builtin_amdgcn_mfma_f32_16x16x32_bf16(af0, Breg[s][1], a01, 0, 0, 0);
                a10 = __builtin_amdgcn_mfma_f32_16x16x32_bf16(af1, Breg[s][0], a10, 0, 0, 0);
                a11 = __builtin_amdgcn_mfma_f32_16x16x32_bf16(af1, Breg[s][1], a11, 0, 0, 0);
            }
        } else {
            // ---- H part: 2-phase pipelined poll + batched A-frag loads ----
            // lane polls producer (kqh*64 + lane); s-group s needs producers 4s..4s+3,
            // so phase 0 (s=0..7) needs ballot bits 0..31, phase 1 needs all 64.
            const int kqh = kq - 2;
            const int* fp = flags + (size_t)t * NWG + kqh * 64 + lane;
            const unsigned short* hb = Hq + ((size_t)(t * BB + arow0)) * HH + kqh * 512 + quad * 8;
            int myf = 0;
            unsigned long long got = 0;

            while ((got & 0xFFFFFFFFull) != 0xFFFFFFFFull) {
                if (!myf) myf = __hip_atomic_load(fp, __ATOMIC_RELAXED, __HIP_MEMORY_SCOPE_AGENT);
                got = __ballot(myf != 0);
                if ((got & 0xFFFFFFFFull) != 0xFFFFFFFFull) __builtin_amdgcn_s_sleep(1);
            }
            asm volatile("" ::: "memory");   // no Hq loads above the flag wait
            bf16x8 af[8][2];
#pragma unroll
            for (int s = 0; s < 8; ++s) {
                af[s][0] = *(const bf16x8*)(hb + s * 32);
                af[s][1] = *(const bf16x8*)(hb + 16 * HH + s * 32);
            }
#pragma unroll
            for (int s = 0; s < 8; ++s) {
                a00 = __builtin_amdgcn_mfma_f32_16x16x32_bf16(af[s][0], Breg[s][0], a00, 0, 0, 0);
                a01 = __builtin_amdgcn_mfma_f32_16x16x32_bf16(af[s][0], Breg[s][1], a01, 0, 0, 0);
                a10 = __builtin_amdgcn_mfma_f32_16x16x32_bf16(af[s][1], Breg[s][0], a10, 0, 0, 0);
                a11 = __builtin_amdgcn_mfma_f32_16x16x32_bf16(af[s][1], Breg[s][1], a11, 0, 0, 0);
            }

            while (got != ~0ull) {
                if (!myf) myf = __hip_atomic_load(fp, __ATOMIC_RELAXED, __HIP_MEMORY_SCOPE_AGENT);
                got = __ballot(myf != 0);
                if (got != ~0ull) __builtin_amdgcn_s_sleep(1);
            }
            asm volatile("" ::: "memory");
#pragma unroll
            for (int s = 0; s < 8; ++s) {
                af[s][0] = *(const bf16x8*)(hb + (8 + s) * 32);
                af[s][1] = *(const bf16x8*)(hb + 16 * HH + (8 + s) * 32);
            }
#pragma unroll
            for (int s = 0; s < 8; ++s) {
                a00 = __builtin_amdgcn_mfma_f32_16x16x32_bf16(af[s][0], Breg[8 + s][0], a00, 0, 0, 0);
                a01 = __builtin_amdgcn_mfma_f32_16x16x32_bf16(af[s][0], Breg[8 + s][1], a01, 0, 0, 0);
                a10 = __builtin_amdgcn_mfma_f32_16x16x32_bf16(af[s][1], Breg[8 + s][0], a10, 0, 0, 0);
                a11 = __builtin_amdgcn_mfma_f32_16x16x32_bf16(af[s][1], Breg[8 + s][1], a11, 0, 0, 0);
            }
        }

        // ---- C-frag (col=l15, row=quad*4+r) -> LDS partials ----
#pragma unroll
        for (int r = 0; r < 4; ++r) {
            int row0 = rhalf * 32 + quad * 4 + r;
            gpart[kq][row0][l15]           = a00[r];
            gpart[kq][row0][16 + l15]      = a01[r];
            gpart[kq][row0 + 16][l15]      = a10[r];
            gpart[kq][row0 + 16][16 + l15] = a11[r];
        }
        __syncthreads();   // A(t): all 4 kq partials visible

        // ---- activation + stores, 128 threads, direct from registers ----
        if (isAct) {
            float hv[4];
#pragma unroll
            for (int j = 0; j < 4; ++j) {
                const int c = ahalf * 4 + j;
                float gi = gpart[0][r2][c]      + gpart[1][r2][c]
                         + gpart[2][r2][c]      + gpart[3][r2][c]      + Bi[j];
                float gf = gpart[0][r2][8 + c]  + gpart[1][r2][8 + c]
                         + gpart[2][r2][8 + c]  + gpart[3][r2][8 + c]  + Bf[j];
                float go = gpart[0][r2][16 + c] + gpart[1][r2][16 + c]
                         + gpart[2][r2][16 + c] + gpart[3][r2][16 + c] + Bo[j];
                float gc = gpart[0][r2][24 + c] + gpart[1][r2][24 + c]
                         + gpart[2][r2][24 + c] + gpart[3][r2][24 + c] + Bc[j];
                float I = sigm(gi), F = sigm(gf), O = sigm(go), G = tanh_f(gc);
                Cr[j] = F * Cr[j] + I * G;
                hv[j] = O * tanh_f(Cr[j]);
            }
            // Hq first (needed by everyone), drain, handshake, flag...
            unsigned long long pk = pack4bf(hv[0], hv[1], hv[2], hv[3]);
            __hip_atomic_store(
                (unsigned long long*)(Hq + ((size_t)(t + 1) * BB + r2) * HH + hcol0),
                pk, __ATOMIC_RELAXED, __HIP_MEMORY_SCOPE_AGENT);
            asm volatile("s_waitcnt vmcnt(0)" ::: "memory");   // Hq acked at LLC
            if (lane == 0) {
                int prev = atomicAdd(&hs, 1);                  // both act waves drained?
                if (prev & 1)
                    __hip_atomic_store(flags + (size_t)(t + 1) * NWG + wg, 1,
                                       __ATOMIC_RELAXED, __HIP_MEMORY_SCOPE_AGENT);
            }
            // ...then the fp32 out stores (ack happens off the critical path)
            float4 v = make_float4(hv[0], hv[1], hv[2], hv[3]);
            *(float4*)(out + ((size_t)t * BB + r2) * HH + hcol0) = v;
            if (t == TT - 1) {   // H_f copy
                *(float4*)(out + (size_t)TT * BB * HH + (size_t)r2 * HH + hcol0) = v;
            }
        }
        __syncthreads();   // B(t): gpart reusable next step
    }

    // ---- C_f ----
    if (isAct) {
        float* cf = out + (size_t)TT * BB * HH + (size_t)BB * HH;
        *(float4*)(cf + (size_t)r2 * HH + hcol0) = make_float4(Cr[0], Cr[1], Cr[2], Cr[3]);
    }
}

// ---------------- launch ----------------
extern "C" void kernel_launch(void* const* d_in, const int* in_sizes, int n_in,
                              void* d_out, int out_size, void* d_ws, size_t ws_size,
                              hipStream_t stream) {
    const float* X   = (const float*)d_in[0];
    const float* H0  = (const float*)d_in[1];
    const float* C0  = (const float*)d_in[2];
    const float* Wxi = (const float*)d_in[3];
    const float* Wxf = (const float*)d_in[4];
    const float* Wxo = (const float*)d_in[5];
    const float* Wxc = (const float*)d_in[6];
    const float* Whi = (const float*)d_in[7];
    const float* Whf = (const float*)d_in[8];
    const float* Who = (const float*)d_in[9];
    const float* Whc = (const float*)d_in[10];
    const float* bi  = (const float*)d_in[11];
    const float* bf_ = (const float*)d_in[12];
    const float* bo  = (const float*)d_in[13];
    const float* bc  = (const float*)d_in[14];

    char* ws = (char*)d_ws;
    unsigned short* Xq  = (unsigned short*)(ws + WS_XQ);
    unsigned short* WhB = (unsigned short*)(ws + WS_WHB);
    unsigned short* Hq  = (unsigned short*)(ws + WS_HQ);
    int* flags          = (int*)(ws + WS_FLAGS);

    hipMemsetAsync(flags, 0, FLAGS_BYTES, stream);

    hipLaunchKernelGGL(cvt_x, dim3(TT * BB * DD / 8 / 256), dim3(256), 0, stream, X, Xq);
    hipLaunchKernelGGL(pack_w, dim3(4096), dim3(256), 0, stream,
                       Wxi, Wxf, Wxo, Wxc, Whi, Whf, Who, Whc, WhB);
    hipLaunchKernelGGL(lstm_seq, dim3(NWG), dim3(512), 0, stream,
                       Xq, WhB, Hq, flags, H0, C0, bi, bf_, bo, bc, (float*)d_out);
}